// Round 8
// baseline (6363.687 us; speedup 1.0000x reference)
//
#include <hip/hip_runtime.h>
#include <float.h>
#include <math.h>

#define NB 4
#define NPTS 8192
#define NS 4096
#define MIDC 32
#define OUTC 64
#define CATC 67
#define BN_EPS 1e-5f
#define TOTAL_PTS (NB*NPTS)   // 32768
#define TOTAL_S (NB*NS)       // 16384

// Packed selection key: for non-negative doubles the IEEE754 bit pattern is
// order-isomorphic to the value. Truncate the low 13 mantissa bits (2^-39 rel
// noise vs ~1e-4 boundary gaps) and store a 13-bit id there: (dist,id) compare
// becomes one f64 compare, and min-update is a single fmin.

__device__ __forceinline__ double packkey(double d, int sp) {
    return __longlong_as_double((__double_as_longlong(d) & 0xFFFFFFFFFFFFE000ULL)
                                | (unsigned long long)sp);
}

// ---------------- stats zero-init (ws is poisoned 0xAA each call) ----------------
__global__ void k_zero(float* __restrict__ stats) {
    for (int i = threadIdx.x; i < 320; i += 256) stats[i] = 0.f;
}

// ---------------- first conv: t1[c][p] = x_in[p] . W1[c] + b1[c] ----------------
__global__ void k_first(const float* __restrict__ xin, const float* __restrict__ W1,
                        const float* __restrict__ b1, float* __restrict__ t1) {
    int p = blockIdx.x * blockDim.x + threadIdx.x;  // 0..32767
    float x = xin[p * 3], y = xin[p * 3 + 1], z = xin[p * 3 + 2];
#pragma unroll
    for (int c = 0; c < MIDC; c++) {
        float v = fmaf(W1[c * 3 + 2], z, fmaf(W1[c * 3 + 1], y, fmaf(W1[c * 3], x, b1[c])));
        t1[c * TOTAL_PTS + p] = v;
    }
}

// ---------------- BN1 stats: one block per channel ----------------
__global__ void k_stats1(const float* __restrict__ t1, float* __restrict__ stats) {
    int c = blockIdx.x, tid = threadIdx.x;
    float s = 0.f, ss = 0.f;
    for (int i = tid; i < TOTAL_PTS; i += 256) {
        float v = t1[c * TOTAL_PTS + i];
        s += v; ss = fmaf(v, v, ss);
    }
#pragma unroll
    for (int off = 32; off; off >>= 1) { s += __shfl_down(s, off); ss += __shfl_down(ss, off); }
    __shared__ float ls[4], lss[4];
    int w = tid >> 6, lane = tid & 63;
    if (lane == 0) { ls[w] = s; lss[w] = ss; }
    __syncthreads();
    if (tid == 0) {
        s = ls[0] + ls[1] + ls[2] + ls[3];
        ss = lss[0] + lss[1] + lss[2] + lss[3];
        float m = s / (float)TOTAL_PTS;
        float var = ss / (float)TOTAL_PTS - m * m;
        stats[c] = m;
        stats[32 + c] = rsqrtf(var + BN_EPS);
    }
}

// ---------------- BN1+ReLU then second conv: feat[p][o] ----------------
__global__ void __launch_bounds__(256) k_feat(const float* __restrict__ t1, const float* __restrict__ stats,
                                              const float* __restrict__ g1, const float* __restrict__ be1,
                                              const float* __restrict__ W2, const float* __restrict__ b2,
                                              float* __restrict__ feat) {
    __shared__ float W2s[OUTC * MIDC];
    for (int i = threadIdx.x; i < OUTC * MIDC; i += 256) W2s[i] = W2[i];
    __syncthreads();
    int p = blockIdx.x * blockDim.x + threadIdx.x;
    float h[MIDC];
#pragma unroll
    for (int c = 0; c < MIDC; c++) {
        float v = t1[c * TOTAL_PTS + p];
        v = fmaf((v - stats[c]) * stats[32 + c], g1[c], be1[c]);
        h[c] = fmaxf(v, 0.f);
    }
#pragma unroll 4
    for (int o = 0; o < OUTC; o++) {
        float a = b2[o];
#pragma unroll
        for (int c = 0; c < MIDC; c++) a = fmaf(W2s[o * MIDC + c], h[c], a);
        feat[p * OUTC + o] = a;
    }
}

// ---------------- farthest point sampling: Morton-clustered lazy-exact ----------------
// 512 threads x 16 pts. One-time: in-kernel Morton bitonic sort so each thread
// owns a spatially tight 16-pt cluster (box in registers). Per step: skip the
// whole cluster iff dmin(c, box)^2 * (1-1e-9) > max_j dk[j] -- provably no
// min-update change, keys bit-exact, so the selection sequence is unchanged.
// LDS sigma-swizzle slot = tid | (j<<9): update-loop b128 reads are
// lane-consecutive (conflict-free; r7's layout was 8-way conflicted).
// A buggy sort would only reduce skip-rate, never correctness: boxes come from
// the actually-owned points and compare-exchange preserves the permutation.
__device__ __forceinline__ unsigned int mpart(unsigned int x) {
    x &= 1023u;
    x = (x | (x << 16)) & 0x030000FFu;
    x = (x | (x << 8))  & 0x0300F00Fu;
    x = (x | (x << 4))  & 0x030C30C3u;
    x = (x | (x << 2))  & 0x09249249u;
    return x;
}

__global__ void __launch_bounds__(512, 2) k_fps(const float* __restrict__ xin, int* __restrict__ fidx) {
    const int b = blockIdx.x;
    const int tid = threadIdx.x;
    const int lane = tid & 63, w = tid >> 6;  // 8 waves
    const float* xb = xin + (size_t)b * NPTS * 3;
    __shared__ union UU {
        struct SS {
            float4 spts[NPTS];       // 131072 B, sigma-swizzled, .w = orig idx bits
            double swd[2][8];        // 128 B
            float  bbx[8][6];        // 192 B
        } s;
        unsigned long long karr[NPTS];  // 65536 B, phases 0-2 only (overlaps spts)
    } u;

    // ---- phase 0: batch bbox ----
    float mnx = FLT_MAX, mny = FLT_MAX, mnz = FLT_MAX;
    float mxx = -FLT_MAX, mxy = -FLT_MAX, mxz = -FLT_MAX;
    for (int j = 0; j < 16; j++) {
        int p = tid + (j << 9);
        float x = xb[p * 3], y = xb[p * 3 + 1], z = xb[p * 3 + 2];
        mnx = fminf(mnx, x); mny = fminf(mny, y); mnz = fminf(mnz, z);
        mxx = fmaxf(mxx, x); mxy = fmaxf(mxy, y); mxz = fmaxf(mxz, z);
    }
#pragma unroll
    for (int off = 32; off; off >>= 1) {
        mnx = fminf(mnx, __shfl_xor(mnx, off)); mny = fminf(mny, __shfl_xor(mny, off));
        mnz = fminf(mnz, __shfl_xor(mnz, off));
        mxx = fmaxf(mxx, __shfl_xor(mxx, off)); mxy = fmaxf(mxy, __shfl_xor(mxy, off));
        mxz = fmaxf(mxz, __shfl_xor(mxz, off));
    }
    if (lane == 0) {
        u.s.bbx[w][0] = mnx; u.s.bbx[w][1] = mny; u.s.bbx[w][2] = mnz;
        u.s.bbx[w][3] = mxx; u.s.bbx[w][4] = mxy; u.s.bbx[w][5] = mxz;
    }
    __syncthreads();
#pragma unroll
    for (int i = 0; i < 8; i++) {
        mnx = fminf(mnx, u.s.bbx[i][0]); mny = fminf(mny, u.s.bbx[i][1]);
        mnz = fminf(mnz, u.s.bbx[i][2]);
        mxx = fmaxf(mxx, u.s.bbx[i][3]); mxy = fmaxf(mxy, u.s.bbx[i][4]);
        mxz = fmaxf(mxz, u.s.bbx[i][5]);
    }
    float scx = 1023.0f / fmaxf(mxx - mnx, 1e-20f);
    float scy = 1023.0f / fmaxf(mxy - mny, 1e-20f);
    float scz = 1023.0f / fmaxf(mxz - mnz, 1e-20f);
    __syncthreads();

    // ---- phase 1: Morton keys + bitonic sort ----
    for (int j = 0; j < 16; j++) {
        int p = tid + (j << 9);
        float x = xb[p * 3], y = xb[p * 3 + 1], z = xb[p * 3 + 2];
        unsigned int ix = (unsigned int)min(1023, max(0, (int)((x - mnx) * scx)));
        unsigned int iy = (unsigned int)min(1023, max(0, (int)((y - mny) * scy)));
        unsigned int iz = (unsigned int)min(1023, max(0, (int)((z - mnz) * scz)));
        unsigned long long code = (unsigned long long)((mpart(ix) << 2) | (mpart(iy) << 1) | mpart(iz));
        u.karr[p] = (code << 13) | (unsigned long long)p;
    }
    __syncthreads();
    for (int k = 2; k <= NPTS; k <<= 1) {
        for (int jj = k >> 1; jj > 0; jj >>= 1) {
            for (int pos = tid; pos < NPTS; pos += 512) {
                int l2 = pos ^ jj;
                if (l2 > pos) {
                    unsigned long long a = u.karr[pos], c = u.karr[l2];
                    bool up = ((pos & k) == 0);
                    if ((up && a > c) || (!up && a < c)) { u.karr[pos] = c; u.karr[l2] = a; }
                }
            }
            __syncthreads();
        }
    }

    // ---- phase 2: gather sorted points into swizzled LDS, per-thread box ----
    unsigned long long kk[16];
#pragma unroll
    for (int j = 0; j < 16; j++) kk[j] = u.karr[tid * 16 + j];
    __syncthreads();  // all karr reads done; spts writes may clobber it
    float blox = FLT_MAX, bloy = FLT_MAX, bloz = FLT_MAX;
    float bhix = -FLT_MAX, bhiy = -FLT_MAX, bhiz = -FLT_MAX;
    double dk[16];
#pragma unroll
    for (int j = 0; j < 16; j++) {
        int oi = (int)(kk[j] & 0x1FFFULL);
        float x = xb[oi * 3], y = xb[oi * 3 + 1], z = xb[oi * 3 + 2];
        int sp = tid * 16 + j;
        int slot = (sp >> 4) | ((sp & 15) << 9);
        u.s.spts[slot] = make_float4(x, y, z, __int_as_float(oi));
        blox = fminf(blox, x); bloy = fminf(bloy, y); bloz = fminf(bloz, z);
        bhix = fmaxf(bhix, x); bhiy = fmaxf(bhiy, y); bhiz = fmaxf(bhiz, z);
        dk[j] = packkey(1e10, sp);
    }
    double lox = (double)blox, loy = (double)bloy, loz = (double)bloz;
    double hix = (double)bhix, hiy = (double)bhiy, hiz = (double)bhiz;
    if (tid == 0) fidx[b * NS] = 0;
    __syncthreads();

    // ---- phase 3: main loop ----
    double cx = (double)xb[0], cy = (double)xb[1], cz = (double)xb[2];
    double tmax = packkey(1e10, tid * 16 + 15);
    for (int t = 1; t < NS; t++) {
        // conservative skip test: provably no dk change for this cluster
        double ex = fmax(fmax(lox - cx, cx - hix), 0.0);
        double ey = fmax(fmax(loy - cy, cy - hiy), 0.0);
        double ez = fmax(fmax(loz - cz, cz - hiz), 0.0);
        double dmsq = fma(ex, ex, fma(ey, ey, ez * ez));
        double tupper = __longlong_as_double(__double_as_longlong(tmax) | 0x1FFFULL);
        if (!(dmsq * 0.999999999 > tupper)) {
            double t0 = 0.0, t1 = 0.0;
#pragma unroll
            for (int j = 0; j < 16; j += 2) {
                float4 v0 = u.s.spts[tid | (j << 9)];
                float4 v1 = u.s.spts[tid | ((j + 1) << 9)];
                double dx0 = (double)v0.x - cx, dy0 = (double)v0.y - cy, dz0 = (double)v0.z - cz;
                double d0 = fma(dx0, dx0, fma(dy0, dy0, dz0 * dz0));
                double nk0 = fmin(dk[j], packkey(d0, tid * 16 + j));
                dk[j] = nk0; t0 = fmax(t0, nk0);
                double dx1 = (double)v1.x - cx, dy1 = (double)v1.y - cy, dz1 = (double)v1.z - cz;
                double d1 = fma(dx1, dx1, fma(dy1, dy1, dz1 * dz1));
                double nk1 = fmin(dk[j + 1], packkey(d1, tid * 16 + j + 1));
                dk[j + 1] = nk1; t1 = fmax(t1, nk1);
            }
            tmax = fmax(t0, t1);
        }
        double wm = tmax;
#pragma unroll
        for (int off = 32; off; off >>= 1)
            wm = fmax(wm, __shfl_xor(wm, off));
        if (lane == 0) u.s.swd[t & 1][w] = wm;
        __syncthreads();
        double m0 = fmax(fmax(u.s.swd[t & 1][0], u.s.swd[t & 1][1]),
                         fmax(u.s.swd[t & 1][2], u.s.swd[t & 1][3]));
        double m1 = fmax(fmax(u.s.swd[t & 1][4], u.s.swd[t & 1][5]),
                         fmax(u.s.swd[t & 1][6], u.s.swd[t & 1][7]));
        double gm = fmax(m0, m1);
        int sp = (int)((unsigned int)__double_as_longlong(gm) & 0x1FFFu);
        float4 cw = u.s.spts[(sp >> 4) | ((sp & 15) << 9)];  // same addr all lanes: broadcast
        cx = (double)cw.x; cy = (double)cw.y; cz = (double)cw.z;
        if (tid == 0) fidx[b * NS + t] = __float_as_int(cw.w);
    }
}

// ---------------- brute-force kNN top-16, packed keys, 4-way ref split ----------------
#define KT2 1024
__global__ void __launch_bounds__(256) k_knn(const float* __restrict__ xin, const int* __restrict__ fidx,
                                             int* __restrict__ knn) {
    __shared__ double sxd[KT2], syd[KT2], szd[KT2];     // 24 KB
    __shared__ double mk[4][16][64];                     // 32 KB: [part][rank][query]
    int tid = threadIdx.x;
    int part = tid >> 6;
    int ql = tid & 63;
    int gq = blockIdx.x * 64 + ql;
    int b = gq >> 12;
    const float* xb = xin + (size_t)b * NPTS * 3;
    int qi = fidx[gq];
    double qx = (double)xb[qi * 3], qy = (double)xb[qi * 3 + 1], qz = (double)xb[qi * 3 + 2];
    double kd0 = DBL_MAX, kd1 = DBL_MAX, kd2 = DBL_MAX, kd3 = DBL_MAX,
           kd4 = DBL_MAX, kd5 = DBL_MAX, kd6 = DBL_MAX, kd7 = DBL_MAX,
           kd8 = DBL_MAX, kd9 = DBL_MAX, kd10 = DBL_MAX, kd11 = DBL_MAX,
           kd12 = DBL_MAX, kd13 = DBL_MAX, kd14 = DBL_MAX, kd15 = DBL_MAX;
    for (int tile = 0; tile < NPTS / KT2; tile++) {
        for (int m = tid; m < KT2; m += 256) {
            int gj = tile * KT2 + m;
            sxd[m] = (double)xb[gj * 3];
            syd[m] = (double)xb[gj * 3 + 1];
            szd[m] = (double)xb[gj * 3 + 2];
        }
        __syncthreads();
        int base = part * (KT2 / 4);
        for (int m = 0; m < KT2 / 4; m++) {
            int li = base + m;
            double dx = qx - sxd[li], dy = qy - syd[li], dz = qz - szd[li];
            double d = fma(dx, dx, fma(dy, dy, dz * dz));
            double key = __longlong_as_double(
                (__double_as_longlong(d) & 0xFFFFFFFFFFFFE000ULL)
                | (unsigned long long)(tile * KT2 + li));
            if (key < kd15) {
                kd15 = fmax(kd14, fmin(kd15, key)); kd14 = fmax(kd13, fmin(kd14, key));
                kd13 = fmax(kd12, fmin(kd13, key)); kd12 = fmax(kd11, fmin(kd12, key));
                kd11 = fmax(kd10, fmin(kd11, key)); kd10 = fmax(kd9,  fmin(kd10, key));
                kd9  = fmax(kd8,  fmin(kd9,  key)); kd8  = fmax(kd7,  fmin(kd8,  key));
                kd7  = fmax(kd6,  fmin(kd7,  key)); kd6  = fmax(kd5,  fmin(kd6,  key));
                kd5  = fmax(kd4,  fmin(kd5,  key)); kd4  = fmax(kd3,  fmin(kd4,  key));
                kd3  = fmax(kd2,  fmin(kd3,  key)); kd2  = fmax(kd1,  fmin(kd2,  key));
                kd1  = fmax(kd0,  fmin(kd1,  key)); kd0  = fmin(kd0,  key);
            }
        }
        __syncthreads();
    }
    mk[part][0][ql] = kd0;  mk[part][1][ql] = kd1;  mk[part][2][ql] = kd2;  mk[part][3][ql] = kd3;
    mk[part][4][ql] = kd4;  mk[part][5][ql] = kd5;  mk[part][6][ql] = kd6;  mk[part][7][ql] = kd7;
    mk[part][8][ql] = kd8;  mk[part][9][ql] = kd9;  mk[part][10][ql] = kd10; mk[part][11][ql] = kd11;
    mk[part][12][ql] = kd12; mk[part][13][ql] = kd13; mk[part][14][ql] = kd14; mk[part][15][ql] = kd15;
    __syncthreads();
    if (tid < 64) {
        int i0 = 0, i1 = 0, i2 = 0, i3 = 0;
        double h0 = mk[0][0][tid], h1 = mk[1][0][tid], h2 = mk[2][0][tid], h3 = mk[3][0][tid];
        int* outp = knn + (size_t)(blockIdx.x * 64 + tid) * 16;
#pragma unroll
        for (int k = 0; k < 16; k++) {
            double mm = fmin(fmin(h0, h1), fmin(h2, h3));
            outp[k] = (int)(__double_as_longlong(mm) & 0x1FFFULL);
            if (mm == h0)      { i0++; h0 = (i0 < 16) ? mk[0][i0][tid] : DBL_MAX; }
            else if (mm == h1) { i1++; h1 = (i1 < 16) ? mk[1][i1][tid] : DBL_MAX; }
            else if (mm == h2) { i2++; h2 = (i2 < 16) ? mk[2][i2][tid] : DBL_MAX; }
            else               { i3++; h3 = (i3 < 16) ? mk[3][i3][tid] : DBL_MAX; }
        }
    }
}

// ---------------- gather + maxpool(67) + conv3 (wave per point) ----------------
__global__ void __launch_bounds__(256) k_group(const float* __restrict__ xin, const float* __restrict__ feat,
                                               const int* __restrict__ fidx, const int* __restrict__ knn,
                                               const float* __restrict__ W3, const float* __restrict__ b3,
                                               float* __restrict__ y3, float* __restrict__ stats) {
    __shared__ float W3s[OUTC * CATC];
    __shared__ float x67[4][68];
    __shared__ float lsum[64], lsq[64];
    int tid = threadIdx.x, w = tid >> 6, lane = tid & 63;
    for (int i = tid; i < OUTC * CATC; i += 256) W3s[i] = W3[i];
    if (tid < 64) { lsum[tid] = 0.f; lsq[tid] = 0.f; }
    __syncthreads();
    float psum = 0.f, psq = 0.f;
    int p0 = blockIdx.x * 64 + w * 16;
    for (int it = 0; it < 16; it++) {
        int p = p0 + it;
        int b = p >> 12;
        int myidx = knn[p * 16 + (lane & 15)];
        int nbk[16];
#pragma unroll
        for (int k = 0; k < 16; k++) nbk[k] = __shfl(myidx, k);
        float m = -FLT_MAX;
#pragma unroll
        for (int k = 0; k < 16; k++) m = fmaxf(m, feat[(size_t)(b * NPTS + nbk[k]) * OUTC + lane]);
        x67[w][3 + lane] = m;
        if (lane < 3) {
            int ci = fidx[p];
            float cc = xin[(size_t)(b * NPTS + ci) * 3 + lane];
            float mg = -FLT_MAX;
#pragma unroll
            for (int k = 0; k < 16; k++) mg = fmaxf(mg, xin[(size_t)(b * NPTS + nbk[k]) * 3 + lane] - cc);
            x67[w][lane] = mg;
        }
        __syncthreads();
        float acc = b3[lane];
#pragma unroll
        for (int c = 0; c < CATC; c++) acc = fmaf(W3s[lane * CATC + c], x67[w][c], acc);
        y3[(size_t)p * OUTC + lane] = acc;
        psum += acc; psq = fmaf(acc, acc, psq);
        __syncthreads();
    }
    atomicAdd(&lsum[lane], psum);
    atomicAdd(&lsq[lane], psq);
    __syncthreads();
    if (tid < 64) { atomicAdd(&stats[64 + tid], lsum[tid]); atomicAdd(&stats[128 + tid], lsq[tid]); }
}

// ---------------- BN2 finalize ----------------
__global__ void k_stats2(float* __restrict__ stats) {
    int c = threadIdx.x;  // 64
    float m = stats[64 + c] / (float)TOTAL_S;
    float var = stats[128 + c] / (float)TOTAL_S - m * m;
    stats[192 + c] = m;
    stats[256 + c] = rsqrtf(var + BN_EPS);
}

// ---------------- BN2 + ReLU in place on y3 ----------------
__global__ void k_bnrelu2(float* __restrict__ y3, const float* __restrict__ stats,
                          const float* __restrict__ g2, const float* __restrict__ be2) {
    int i = blockIdx.x * blockDim.x + threadIdx.x;
    int c = i & 63;
    float v = y3[i];
    v = fmaf((v - stats[192 + c]) * stats[256 + c], g2[c], be2[c]);
    y3[i] = fmaxf(v, 0.f);
}

// ---------------- final conv: out = y3' @ W4^T + b4 ----------------
__global__ void __launch_bounds__(256) k_last(const float* __restrict__ y3, const float* __restrict__ W4,
                                              const float* __restrict__ b4, float* __restrict__ out) {
    __shared__ float W4t[OUTC * OUTC];
    for (int i = threadIdx.x; i < OUTC * OUTC; i += 256) W4t[(i & 63) * 64 + (i >> 6)] = W4[i];
    __syncthreads();
    int t = blockIdx.x * 256 + threadIdx.x;
    int p = t >> 6, o = t & 63;
    const float* yp = y3 + (size_t)p * OUTC;
    float acc = b4[o];
#pragma unroll
    for (int c = 0; c < OUTC; c++) acc = fmaf(W4t[c * 64 + o], yp[c], acc);
    out[t] = acc;
}

extern "C" void kernel_launch(void* const* d_in, const int* in_sizes, int n_in,
                              void* d_out, int out_size, void* d_ws, size_t ws_size,
                              hipStream_t stream) {
    const float* xin = (const float*)d_in[0];
    const float* W1  = (const float*)d_in[1];
    const float* b1  = (const float*)d_in[2];
    const float* g1  = (const float*)d_in[3];
    const float* be1 = (const float*)d_in[4];
    const float* W2  = (const float*)d_in[5];
    const float* b2  = (const float*)d_in[6];
    const float* W3  = (const float*)d_in[7];
    const float* b3  = (const float*)d_in[8];
    const float* g2  = (const float*)d_in[9];
    const float* be2 = (const float*)d_in[10];
    const float* W4  = (const float*)d_in[11];
    const float* b4  = (const float*)d_in[12];
    float* out = (float*)d_out;

    float* ws = (float*)d_ws;
    float* t1   = ws;                                       // 32*32768   = 1,048,576 f
    float* feat = t1 + (size_t)MIDC * TOTAL_PTS;            // 32768*64   = 2,097,152 f
    int*   fidx = (int*)(feat + (size_t)TOTAL_PTS * OUTC);  // 16384 i
    int*   knn  = fidx + TOTAL_S;                           // 16384*16   = 262,144 i
    float* y3   = (float*)(knn + (size_t)TOTAL_S * 16);     // 16384*64   = 1,048,576 f
    float* stats = y3 + (size_t)TOTAL_S * OUTC;             // 320 f

    k_zero<<<1, 256, 0, stream>>>(stats);
    k_first<<<TOTAL_PTS / 256, 256, 0, stream>>>(xin, W1, b1, t1);
    k_stats1<<<MIDC, 256, 0, stream>>>(t1, stats);
    k_feat<<<TOTAL_PTS / 256, 256, 0, stream>>>(t1, stats, g1, be1, W2, b2, feat);
    k_fps<<<NB, 512, 0, stream>>>(xin, fidx);
    k_knn<<<TOTAL_S / 64, 256, 0, stream>>>(xin, fidx, knn);
    k_group<<<TOTAL_S / 64, 256, 0, stream>>>(xin, feat, fidx, knn, W3, b3, y3, stats);
    k_stats2<<<1, 64, 0, stream>>>(stats);
    k_bnrelu2<<<TOTAL_S * OUTC / 256, 256, 0, stream>>>(y3, stats, g2, be2);
    k_last<<<TOTAL_S * OUTC / 256, 256, 0, stream>>>(y3, W4, b4, out);
}

// Round 9
// 5787.991 us; speedup vs baseline: 1.0995x; 1.0995x over previous
//
#include <hip/hip_runtime.h>
#include <float.h>
#include <math.h>

#define NB 4
#define NPTS 8192
#define NS 4096
#define MIDC 32
#define OUTC 64
#define CATC 67
#define BN_EPS 1e-5f
#define TOTAL_PTS (NB*NPTS)   // 32768
#define TOTAL_S (NB*NS)       // 16384

// Packed selection key: for non-negative doubles the IEEE754 bit pattern is
// order-isomorphic to the value. Truncate the low 13 mantissa bits (2^-39 rel
// noise vs ~1e-4 boundary gaps) and store a 13-bit id there: (dist,id) compare
// becomes one f64 compare, and min-update is a single fmin.

__device__ __forceinline__ double packkey(double d, int sp) {
    return __longlong_as_double((__double_as_longlong(d) & 0xFFFFFFFFFFFFE000ULL)
                                | (unsigned long long)sp);
}

// ---------------- stats zero-init (ws is poisoned 0xAA each call) ----------------
__global__ void k_zero(float* __restrict__ stats) {
    for (int i = threadIdx.x; i < 320; i += 256) stats[i] = 0.f;
}

// ---------------- first conv: t1[c][p] = x_in[p] . W1[c] + b1[c] ----------------
__global__ void k_first(const float* __restrict__ xin, const float* __restrict__ W1,
                        const float* __restrict__ b1, float* __restrict__ t1) {
    int p = blockIdx.x * blockDim.x + threadIdx.x;  // 0..32767
    float x = xin[p * 3], y = xin[p * 3 + 1], z = xin[p * 3 + 2];
#pragma unroll
    for (int c = 0; c < MIDC; c++) {
        float v = fmaf(W1[c * 3 + 2], z, fmaf(W1[c * 3 + 1], y, fmaf(W1[c * 3], x, b1[c])));
        t1[c * TOTAL_PTS + p] = v;
    }
}

// ---------------- BN1 stats: one block per channel ----------------
__global__ void k_stats1(const float* __restrict__ t1, float* __restrict__ stats) {
    int c = blockIdx.x, tid = threadIdx.x;
    float s = 0.f, ss = 0.f;
    for (int i = tid; i < TOTAL_PTS; i += 256) {
        float v = t1[c * TOTAL_PTS + i];
        s += v; ss = fmaf(v, v, ss);
    }
#pragma unroll
    for (int off = 32; off; off >>= 1) { s += __shfl_down(s, off); ss += __shfl_down(ss, off); }
    __shared__ float ls[4], lss[4];
    int w = tid >> 6, lane = tid & 63;
    if (lane == 0) { ls[w] = s; lss[w] = ss; }
    __syncthreads();
    if (tid == 0) {
        s = ls[0] + ls[1] + ls[2] + ls[3];
        ss = lss[0] + lss[1] + lss[2] + lss[3];
        float m = s / (float)TOTAL_PTS;
        float var = ss / (float)TOTAL_PTS - m * m;
        stats[c] = m;
        stats[32 + c] = rsqrtf(var + BN_EPS);
    }
}

// ---------------- BN1+ReLU then second conv: feat[p][o] ----------------
__global__ void __launch_bounds__(256) k_feat(const float* __restrict__ t1, const float* __restrict__ stats,
                                              const float* __restrict__ g1, const float* __restrict__ be1,
                                              const float* __restrict__ W2, const float* __restrict__ b2,
                                              float* __restrict__ feat) {
    __shared__ float W2s[OUTC * MIDC];
    for (int i = threadIdx.x; i < OUTC * MIDC; i += 256) W2s[i] = W2[i];
    __syncthreads();
    int p = blockIdx.x * blockDim.x + threadIdx.x;
    float h[MIDC];
#pragma unroll
    for (int c = 0; c < MIDC; c++) {
        float v = t1[c * TOTAL_PTS + p];
        v = fmaf((v - stats[c]) * stats[32 + c], g1[c], be1[c]);
        h[c] = fmaxf(v, 0.f);
    }
#pragma unroll 4
    for (int o = 0; o < OUTC; o++) {
        float a = b2[o];
#pragma unroll
        for (int c = 0; c < MIDC; c++) a = fmaf(W2s[o * MIDC + c], h[c], a);
        feat[p * OUTC + o] = a;
    }
}

// ---------------- farthest point sampling: Morton-clustered lazy-exact ----------------
// 1024 threads x 8 pts (r8 post-mortem: critical path = winner-wave update;
// halving pts/thread halves it). Morton bitonic sort -> thread owns a tight
// 8-pt cluster (box in regs). Skip cluster iff dmin(c,box)^2*(1-1e-9) >
// max_j dk[j] (provably no change; keys bit-exact -> selection unchanged).
// LDS slot = tid | (j<<10): update reads lane-consecutive (conflict-free).
__device__ __forceinline__ unsigned int mpart(unsigned int x) {
    x &= 1023u;
    x = (x | (x << 16)) & 0x030000FFu;
    x = (x | (x << 8))  & 0x0300F00Fu;
    x = (x | (x << 4))  & 0x030C30C3u;
    x = (x | (x << 2))  & 0x09249249u;
    return x;
}

__global__ void __launch_bounds__(1024) k_fps(const float* __restrict__ xin, int* __restrict__ fidx) {
    const int b = blockIdx.x;
    const int tid = threadIdx.x;
    const int lane = tid & 63, w = tid >> 6;  // 16 waves
    const float* xb = xin + (size_t)b * NPTS * 3;
    __shared__ union UU {
        struct SS {
            float4 spts[NPTS];       // 131072 B, swizzled, .w = orig idx bits
            double swd[2][16];       // 256 B
            float  bbx[16][6];       // 384 B
        } s;
        unsigned long long karr[NPTS];  // 65536 B, phases 0-2 only (overlaps spts)
    } u;

    // ---- phase 0: batch bbox ----
    float mnx = FLT_MAX, mny = FLT_MAX, mnz = FLT_MAX;
    float mxx = -FLT_MAX, mxy = -FLT_MAX, mxz = -FLT_MAX;
    for (int j = 0; j < 8; j++) {
        int p = tid + (j << 10);
        float x = xb[p * 3], y = xb[p * 3 + 1], z = xb[p * 3 + 2];
        mnx = fminf(mnx, x); mny = fminf(mny, y); mnz = fminf(mnz, z);
        mxx = fmaxf(mxx, x); mxy = fmaxf(mxy, y); mxz = fmaxf(mxz, z);
    }
#pragma unroll
    for (int off = 32; off; off >>= 1) {
        mnx = fminf(mnx, __shfl_xor(mnx, off)); mny = fminf(mny, __shfl_xor(mny, off));
        mnz = fminf(mnz, __shfl_xor(mnz, off));
        mxx = fmaxf(mxx, __shfl_xor(mxx, off)); mxy = fmaxf(mxy, __shfl_xor(mxy, off));
        mxz = fmaxf(mxz, __shfl_xor(mxz, off));
    }
    if (lane == 0) {
        u.s.bbx[w][0] = mnx; u.s.bbx[w][1] = mny; u.s.bbx[w][2] = mnz;
        u.s.bbx[w][3] = mxx; u.s.bbx[w][4] = mxy; u.s.bbx[w][5] = mxz;
    }
    __syncthreads();
#pragma unroll
    for (int i = 0; i < 16; i++) {
        mnx = fminf(mnx, u.s.bbx[i][0]); mny = fminf(mny, u.s.bbx[i][1]);
        mnz = fminf(mnz, u.s.bbx[i][2]);
        mxx = fmaxf(mxx, u.s.bbx[i][3]); mxy = fmaxf(mxy, u.s.bbx[i][4]);
        mxz = fmaxf(mxz, u.s.bbx[i][5]);
    }
    float scx = 1023.0f / fmaxf(mxx - mnx, 1e-20f);
    float scy = 1023.0f / fmaxf(mxy - mny, 1e-20f);
    float scz = 1023.0f / fmaxf(mxz - mnz, 1e-20f);
    __syncthreads();

    // ---- phase 1: Morton keys + bitonic sort ----
    for (int j = 0; j < 8; j++) {
        int p = tid + (j << 10);
        float x = xb[p * 3], y = xb[p * 3 + 1], z = xb[p * 3 + 2];
        unsigned int ix = (unsigned int)min(1023, max(0, (int)((x - mnx) * scx)));
        unsigned int iy = (unsigned int)min(1023, max(0, (int)((y - mny) * scy)));
        unsigned int iz = (unsigned int)min(1023, max(0, (int)((z - mnz) * scz)));
        unsigned long long code = (unsigned long long)((mpart(ix) << 2) | (mpart(iy) << 1) | mpart(iz));
        u.karr[p] = (code << 13) | (unsigned long long)p;
    }
    __syncthreads();
    for (int k = 2; k <= NPTS; k <<= 1) {
        for (int jj = k >> 1; jj > 0; jj >>= 1) {
            for (int pos = tid; pos < NPTS; pos += 1024) {
                int l2 = pos ^ jj;
                if (l2 > pos) {
                    unsigned long long a = u.karr[pos], c = u.karr[l2];
                    bool up = ((pos & k) == 0);
                    if ((up && a > c) || (!up && a < c)) { u.karr[pos] = c; u.karr[l2] = a; }
                }
            }
            __syncthreads();
        }
    }

    // ---- phase 2: gather sorted points into swizzled LDS, per-thread box ----
    unsigned long long kk[8];
#pragma unroll
    for (int j = 0; j < 8; j++) kk[j] = u.karr[tid * 8 + j];
    __syncthreads();  // all karr reads done; spts writes may clobber it
    float blox = FLT_MAX, bloy = FLT_MAX, bloz = FLT_MAX;
    float bhix = -FLT_MAX, bhiy = -FLT_MAX, bhiz = -FLT_MAX;
    double dk[8];
#pragma unroll
    for (int j = 0; j < 8; j++) {
        int oi = (int)(kk[j] & 0x1FFFULL);
        float x = xb[oi * 3], y = xb[oi * 3 + 1], z = xb[oi * 3 + 2];
        int sp = tid * 8 + j;
        int slot = (sp >> 3) | ((sp & 7) << 10);
        u.s.spts[slot] = make_float4(x, y, z, __int_as_float(oi));
        blox = fminf(blox, x); bloy = fminf(bloy, y); bloz = fminf(bloz, z);
        bhix = fmaxf(bhix, x); bhiy = fmaxf(bhiy, y); bhiz = fmaxf(bhiz, z);
        dk[j] = packkey(1e10, sp);
    }
    double lox = (double)blox, loy = (double)bloy, loz = (double)bloz;
    double hix = (double)bhix, hiy = (double)bhiy, hiz = (double)bhiz;
    if (tid == 0) fidx[b * NS] = 0;
    __syncthreads();

    // ---- phase 3: main loop ----
    double cx = (double)xb[0], cy = (double)xb[1], cz = (double)xb[2];
    double tmax = packkey(1e10, tid * 8 + 7);
    for (int t = 1; t < NS; t++) {
        // conservative skip test: provably no dk change for this cluster
        double ex = fmax(fmax(lox - cx, cx - hix), 0.0);
        double ey = fmax(fmax(loy - cy, cy - hiy), 0.0);
        double ez = fmax(fmax(loz - cz, cz - hiz), 0.0);
        double dmsq = fma(ex, ex, fma(ey, ey, ez * ez));
        double tupper = __longlong_as_double(__double_as_longlong(tmax) | 0x1FFFULL);
        if (!(dmsq * 0.999999999 > tupper)) {
            double t0 = 0.0, t1 = 0.0;
#pragma unroll
            for (int j = 0; j < 8; j += 2) {
                float4 v0 = u.s.spts[tid | (j << 10)];
                float4 v1 = u.s.spts[tid | ((j + 1) << 10)];
                double dx0 = (double)v0.x - cx, dy0 = (double)v0.y - cy, dz0 = (double)v0.z - cz;
                double d0 = fma(dx0, dx0, fma(dy0, dy0, dz0 * dz0));
                double nk0 = fmin(dk[j], packkey(d0, tid * 8 + j));
                dk[j] = nk0; t0 = fmax(t0, nk0);
                double dx1 = (double)v1.x - cx, dy1 = (double)v1.y - cy, dz1 = (double)v1.z - cz;
                double d1 = fma(dx1, dx1, fma(dy1, dy1, dz1 * dz1));
                double nk1 = fmin(dk[j + 1], packkey(d1, tid * 8 + j + 1));
                dk[j + 1] = nk1; t1 = fmax(t1, nk1);
            }
            tmax = fmax(t0, t1);
        }
        double wm = tmax;
#pragma unroll
        for (int off = 32; off; off >>= 1)
            wm = fmax(wm, __shfl_xor(wm, off));
        if (lane == 0) u.s.swd[t & 1][w] = wm;
        __syncthreads();
        double g0 = fmax(fmax(u.s.swd[t & 1][0], u.s.swd[t & 1][1]),
                         fmax(u.s.swd[t & 1][2], u.s.swd[t & 1][3]));
        double g1 = fmax(fmax(u.s.swd[t & 1][4], u.s.swd[t & 1][5]),
                         fmax(u.s.swd[t & 1][6], u.s.swd[t & 1][7]));
        double g2 = fmax(fmax(u.s.swd[t & 1][8], u.s.swd[t & 1][9]),
                         fmax(u.s.swd[t & 1][10], u.s.swd[t & 1][11]));
        double g3 = fmax(fmax(u.s.swd[t & 1][12], u.s.swd[t & 1][13]),
                         fmax(u.s.swd[t & 1][14], u.s.swd[t & 1][15]));
        double gm = fmax(fmax(g0, g1), fmax(g2, g3));
        int sp = (int)((unsigned int)__double_as_longlong(gm) & 0x1FFFu);
        float4 cw = u.s.spts[(sp >> 3) | ((sp & 7) << 10)];  // same addr all lanes: broadcast
        cx = (double)cw.x; cy = (double)cw.y; cz = (double)cw.z;
        if (tid == 0) fidx[b * NS + t] = __float_as_int(cw.w);
    }
}

// ---------------- brute-force kNN top-16, packed keys, 4-way ref split ----------------
#define KT2 1024
__global__ void __launch_bounds__(256) k_knn(const float* __restrict__ xin, const int* __restrict__ fidx,
                                             int* __restrict__ knn) {
    __shared__ double sxd[KT2], syd[KT2], szd[KT2];     // 24 KB
    __shared__ double mk[4][16][64];                     // 32 KB: [part][rank][query]
    int tid = threadIdx.x;
    int part = tid >> 6;
    int ql = tid & 63;
    int gq = blockIdx.x * 64 + ql;
    int b = gq >> 12;
    const float* xb = xin + (size_t)b * NPTS * 3;
    int qi = fidx[gq];
    double qx = (double)xb[qi * 3], qy = (double)xb[qi * 3 + 1], qz = (double)xb[qi * 3 + 2];
    double kd0 = DBL_MAX, kd1 = DBL_MAX, kd2 = DBL_MAX, kd3 = DBL_MAX,
           kd4 = DBL_MAX, kd5 = DBL_MAX, kd6 = DBL_MAX, kd7 = DBL_MAX,
           kd8 = DBL_MAX, kd9 = DBL_MAX, kd10 = DBL_MAX, kd11 = DBL_MAX,
           kd12 = DBL_MAX, kd13 = DBL_MAX, kd14 = DBL_MAX, kd15 = DBL_MAX;
    for (int tile = 0; tile < NPTS / KT2; tile++) {
        for (int m = tid; m < KT2; m += 256) {
            int gj = tile * KT2 + m;
            sxd[m] = (double)xb[gj * 3];
            syd[m] = (double)xb[gj * 3 + 1];
            szd[m] = (double)xb[gj * 3 + 2];
        }
        __syncthreads();
        int base = part * (KT2 / 4);
        for (int m = 0; m < KT2 / 4; m++) {
            int li = base + m;
            double dx = qx - sxd[li], dy = qy - syd[li], dz = qz - szd[li];
            double d = fma(dx, dx, fma(dy, dy, dz * dz));
            double key = __longlong_as_double(
                (__double_as_longlong(d) & 0xFFFFFFFFFFFFE000ULL)
                | (unsigned long long)(tile * KT2 + li));
            if (key < kd15) {
                kd15 = fmax(kd14, fmin(kd15, key)); kd14 = fmax(kd13, fmin(kd14, key));
                kd13 = fmax(kd12, fmin(kd13, key)); kd12 = fmax(kd11, fmin(kd12, key));
                kd11 = fmax(kd10, fmin(kd11, key)); kd10 = fmax(kd9,  fmin(kd10, key));
                kd9  = fmax(kd8,  fmin(kd9,  key)); kd8  = fmax(kd7,  fmin(kd8,  key));
                kd7  = fmax(kd6,  fmin(kd7,  key)); kd6  = fmax(kd5,  fmin(kd6,  key));
                kd5  = fmax(kd4,  fmin(kd5,  key)); kd4  = fmax(kd3,  fmin(kd4,  key));
                kd3  = fmax(kd2,  fmin(kd3,  key)); kd2  = fmax(kd1,  fmin(kd2,  key));
                kd1  = fmax(kd0,  fmin(kd1,  key)); kd0  = fmin(kd0,  key);
            }
        }
        __syncthreads();
    }
    mk[part][0][ql] = kd0;  mk[part][1][ql] = kd1;  mk[part][2][ql] = kd2;  mk[part][3][ql] = kd3;
    mk[part][4][ql] = kd4;  mk[part][5][ql] = kd5;  mk[part][6][ql] = kd6;  mk[part][7][ql] = kd7;
    mk[part][8][ql] = kd8;  mk[part][9][ql] = kd9;  mk[part][10][ql] = kd10; mk[part][11][ql] = kd11;
    mk[part][12][ql] = kd12; mk[part][13][ql] = kd13; mk[part][14][ql] = kd14; mk[part][15][ql] = kd15;
    __syncthreads();
    if (tid < 64) {
        int i0 = 0, i1 = 0, i2 = 0, i3 = 0;
        double h0 = mk[0][0][tid], h1 = mk[1][0][tid], h2 = mk[2][0][tid], h3 = mk[3][0][tid];
        int* outp = knn + (size_t)(blockIdx.x * 64 + tid) * 16;
#pragma unroll
        for (int k = 0; k < 16; k++) {
            double mm = fmin(fmin(h0, h1), fmin(h2, h3));
            outp[k] = (int)(__double_as_longlong(mm) & 0x1FFFULL);
            if (mm == h0)      { i0++; h0 = (i0 < 16) ? mk[0][i0][tid] : DBL_MAX; }
            else if (mm == h1) { i1++; h1 = (i1 < 16) ? mk[1][i1][tid] : DBL_MAX; }
            else if (mm == h2) { i2++; h2 = (i2 < 16) ? mk[2][i2][tid] : DBL_MAX; }
            else               { i3++; h3 = (i3 < 16) ? mk[3][i3][tid] : DBL_MAX; }
        }
    }
}

// ---------------- gather + maxpool(67) + conv3 (wave per point) ----------------
__global__ void __launch_bounds__(256) k_group(const float* __restrict__ xin, const float* __restrict__ feat,
                                               const int* __restrict__ fidx, const int* __restrict__ knn,
                                               const float* __restrict__ W3, const float* __restrict__ b3,
                                               float* __restrict__ y3, float* __restrict__ stats) {
    __shared__ float W3s[OUTC * CATC];
    __shared__ float x67[4][68];
    __shared__ float lsum[64], lsq[64];
    int tid = threadIdx.x, w = tid >> 6, lane = tid & 63;
    for (int i = tid; i < OUTC * CATC; i += 256) W3s[i] = W3[i];
    if (tid < 64) { lsum[tid] = 0.f; lsq[tid] = 0.f; }
    __syncthreads();
    float psum = 0.f, psq = 0.f;
    int p0 = blockIdx.x * 64 + w * 16;
    for (int it = 0; it < 16; it++) {
        int p = p0 + it;
        int b = p >> 12;
        int myidx = knn[p * 16 + (lane & 15)];
        int nbk[16];
#pragma unroll
        for (int k = 0; k < 16; k++) nbk[k] = __shfl(myidx, k);
        float m = -FLT_MAX;
#pragma unroll
        for (int k = 0; k < 16; k++) m = fmaxf(m, feat[(size_t)(b * NPTS + nbk[k]) * OUTC + lane]);
        x67[w][3 + lane] = m;
        if (lane < 3) {
            int ci = fidx[p];
            float cc = xin[(size_t)(b * NPTS + ci) * 3 + lane];
            float mg = -FLT_MAX;
#pragma unroll
            for (int k = 0; k < 16; k++) mg = fmaxf(mg, xin[(size_t)(b * NPTS + nbk[k]) * 3 + lane] - cc);
            x67[w][lane] = mg;
        }
        __syncthreads();
        float acc = b3[lane];
#pragma unroll
        for (int c = 0; c < CATC; c++) acc = fmaf(W3s[lane * CATC + c], x67[w][c], acc);
        y3[(size_t)p * OUTC + lane] = acc;
        psum += acc; psq = fmaf(acc, acc, psq);
        __syncthreads();
    }
    atomicAdd(&lsum[lane], psum);
    atomicAdd(&lsq[lane], psq);
    __syncthreads();
    if (tid < 64) { atomicAdd(&stats[64 + tid], lsum[tid]); atomicAdd(&stats[128 + tid], lsq[tid]); }
}

// ---------------- BN2 finalize ----------------
__global__ void k_stats2(float* __restrict__ stats) {
    int c = threadIdx.x;  // 64
    float m = stats[64 + c] / (float)TOTAL_S;
    float var = stats[128 + c] / (float)TOTAL_S - m * m;
    stats[192 + c] = m;
    stats[256 + c] = rsqrtf(var + BN_EPS);
}

// ---------------- BN2 + ReLU in place on y3 ----------------
__global__ void k_bnrelu2(float* __restrict__ y3, const float* __restrict__ stats,
                          const float* __restrict__ g2, const float* __restrict__ be2) {
    int i = blockIdx.x * blockDim.x + threadIdx.x;
    int c = i & 63;
    float v = y3[i];
    v = fmaf((v - stats[192 + c]) * stats[256 + c], g2[c], be2[c]);
    y3[i] = fmaxf(v, 0.f);
}

// ---------------- final conv: out = y3' @ W4^T + b4 ----------------
__global__ void __launch_bounds__(256) k_last(const float* __restrict__ y3, const float* __restrict__ W4,
                                              const float* __restrict__ b4, float* __restrict__ out) {
    __shared__ float W4t[OUTC * OUTC];
    for (int i = threadIdx.x; i < OUTC * OUTC; i += 256) W4t[(i & 63) * 64 + (i >> 6)] = W4[i];
    __syncthreads();
    int t = blockIdx.x * 256 + threadIdx.x;
    int p = t >> 6, o = t & 63;
    const float* yp = y3 + (size_t)p * OUTC;
    float acc = b4[o];
#pragma unroll
    for (int c = 0; c < OUTC; c++) acc = fmaf(W4t[c * 64 + o], yp[c], acc);
    out[t] = acc;
}

extern "C" void kernel_launch(void* const* d_in, const int* in_sizes, int n_in,
                              void* d_out, int out_size, void* d_ws, size_t ws_size,
                              hipStream_t stream) {
    const float* xin = (const float*)d_in[0];
    const float* W1  = (const float*)d_in[1];
    const float* b1  = (const float*)d_in[2];
    const float* g1  = (const float*)d_in[3];
    const float* be1 = (const float*)d_in[4];
    const float* W2  = (const float*)d_in[5];
    const float* b2  = (const float*)d_in[6];
    const float* W3  = (const float*)d_in[7];
    const float* b3  = (const float*)d_in[8];
    const float* g2  = (const float*)d_in[9];
    const float* be2 = (const float*)d_in[10];
    const float* W4  = (const float*)d_in[11];
    const float* b4  = (const float*)d_in[12];
    float* out = (float*)d_out;

    float* ws = (float*)d_ws;
    float* t1   = ws;                                       // 32*32768   = 1,048,576 f
    float* feat = t1 + (size_t)MIDC * TOTAL_PTS;            // 32768*64   = 2,097,152 f
    int*   fidx = (int*)(feat + (size_t)TOTAL_PTS * OUTC);  // 16384 i
    int*   knn  = fidx + TOTAL_S;                           // 16384*16   = 262,144 i
    float* y3   = (float*)(knn + (size_t)TOTAL_S * 16);     // 16384*64   = 1,048,576 f
    float* stats = y3 + (size_t)TOTAL_S * OUTC;             // 320 f

    k_zero<<<1, 256, 0, stream>>>(stats);
    k_first<<<TOTAL_PTS / 256, 256, 0, stream>>>(xin, W1, b1, t1);
    k_stats1<<<MIDC, 256, 0, stream>>>(t1, stats);
    k_feat<<<TOTAL_PTS / 256, 256, 0, stream>>>(t1, stats, g1, be1, W2, b2, feat);
    k_fps<<<NB, 1024, 0, stream>>>(xin, fidx);
    k_knn<<<TOTAL_S / 64, 256, 0, stream>>>(xin, fidx, knn);
    k_group<<<TOTAL_S / 64, 256, 0, stream>>>(xin, feat, fidx, knn, W3, b3, y3, stats);
    k_stats2<<<1, 64, 0, stream>>>(stats);
    k_bnrelu2<<<TOTAL_S * OUTC / 256, 256, 0, stream>>>(y3, stats, g2, be2);
    k_last<<<TOTAL_S * OUTC / 256, 256, 0, stream>>>(y3, W4, b4, out);
}

// Round 10
// 5171.314 us; speedup vs baseline: 1.2306x; 1.1192x over previous
//
#include <hip/hip_runtime.h>
#include <float.h>
#include <math.h>

#define NB 4
#define NPTS 8192
#define NS 4096
#define MIDC 32
#define OUTC 64
#define CATC 67
#define BN_EPS 1e-5f
#define TOTAL_PTS (NB*NPTS)   // 32768
#define TOTAL_S (NB*NS)       // 16384

// Packed selection key: for non-negative doubles the IEEE754 bit pattern is
// order-isomorphic to the value. Truncate the low 13 mantissa bits (2^-39 rel
// noise vs ~1e-4 boundary gaps) and store a 13-bit id there: (dist,id) compare
// becomes one f64 compare, and min-update is a single fmin.

__device__ __forceinline__ double packkey(double d, int sp) {
    return __longlong_as_double((__double_as_longlong(d) & 0xFFFFFFFFFFFFE000ULL)
                                | (unsigned long long)sp);
}

// ---------------- first conv: t1[c][p] = x_in[p] . W1[c] + b1[c] ----------------
__global__ void k_first(const float* __restrict__ xin, const float* __restrict__ W1,
                        const float* __restrict__ b1, float* __restrict__ t1) {
    int p = blockIdx.x * blockDim.x + threadIdx.x;  // 0..32767
    float x = xin[p * 3], y = xin[p * 3 + 1], z = xin[p * 3 + 2];
#pragma unroll
    for (int c = 0; c < MIDC; c++) {
        float v = fmaf(W1[c * 3 + 2], z, fmaf(W1[c * 3 + 1], y, fmaf(W1[c * 3], x, b1[c])));
        t1[c * TOTAL_PTS + p] = v;
    }
}

// ---------------- BN1 stats: one block per channel (+ zero stats[64..320)) ----------------
__global__ void k_stats1(const float* __restrict__ t1, float* __restrict__ stats) {
    int c = blockIdx.x, tid = threadIdx.x;
    if (tid < 8) stats[64 + c * 8 + tid] = 0.f;   // ws is poisoned 0xAA each call
    float s = 0.f, ss = 0.f;
    for (int i = tid; i < TOTAL_PTS; i += 256) {
        float v = t1[c * TOTAL_PTS + i];
        s += v; ss = fmaf(v, v, ss);
    }
#pragma unroll
    for (int off = 32; off; off >>= 1) { s += __shfl_down(s, off); ss += __shfl_down(ss, off); }
    __shared__ float ls[4], lss[4];
    int w = tid >> 6, lane = tid & 63;
    if (lane == 0) { ls[w] = s; lss[w] = ss; }
    __syncthreads();
    if (tid == 0) {
        s = ls[0] + ls[1] + ls[2] + ls[3];
        ss = lss[0] + lss[1] + lss[2] + lss[3];
        float m = s / (float)TOTAL_PTS;
        float var = ss / (float)TOTAL_PTS - m * m;
        stats[c] = m;
        stats[32 + c] = rsqrtf(var + BN_EPS);
    }
}

// ---------------- BN1+ReLU then second conv: feat[p][o] ----------------
__global__ void __launch_bounds__(256) k_feat(const float* __restrict__ t1, const float* __restrict__ stats,
                                              const float* __restrict__ g1, const float* __restrict__ be1,
                                              const float* __restrict__ W2, const float* __restrict__ b2,
                                              float* __restrict__ feat) {
    __shared__ float W2s[OUTC * MIDC];
    for (int i = threadIdx.x; i < OUTC * MIDC; i += 256) W2s[i] = W2[i];
    __syncthreads();
    int p = blockIdx.x * blockDim.x + threadIdx.x;
    float h[MIDC];
#pragma unroll
    for (int c = 0; c < MIDC; c++) {
        float v = t1[c * TOTAL_PTS + p];
        v = fmaf((v - stats[c]) * stats[32 + c], g1[c], be1[c]);
        h[c] = fmaxf(v, 0.f);
    }
#pragma unroll 4
    for (int o = 0; o < OUTC; o++) {
        float a = b2[o];
#pragma unroll
        for (int c = 0; c < MIDC; c++) a = fmaf(W2s[o * MIDC + c], h[c], a);
        feat[p * OUTC + o] = a;
    }
}

// ---------------- farthest point sampling: Morton-clustered lazy-exact ----------------
// 1024 threads x 8 pts. r9 post-mortem: floor = all-wave per-step scaffolding.
// This round: (1) f32 conservative skip test (box/centroid are exact input
// floats; x0.99999 margin >> 5-ulp error -> never skips a true update);
// (2) butterfly only when the wave updated (skipped wave's max is unchanged;
// winner's wave always updates since its box contains c);
// (3) final reduce = 1 LDS read + 4-level 16-lane shuffle, all lanes get gm.
// All dk/selection math stays f64 bit-exact -> selection sequence unchanged.
__device__ __forceinline__ unsigned int mpart(unsigned int x) {
    x &= 1023u;
    x = (x | (x << 16)) & 0x030000FFu;
    x = (x | (x << 8))  & 0x0300F00Fu;
    x = (x | (x << 4))  & 0x030C30C3u;
    x = (x | (x << 2))  & 0x09249249u;
    return x;
}

__global__ void __launch_bounds__(1024) k_fps(const float* __restrict__ xin, int* __restrict__ fidx) {
    const int b = blockIdx.x;
    const int tid = threadIdx.x;
    const int lane = tid & 63, w = tid >> 6;  // 16 waves
    const float* xb = xin + (size_t)b * NPTS * 3;
    __shared__ union UU {
        struct SS {
            float4 spts[NPTS];       // 131072 B, swizzled, .w = orig idx bits
            double swd[2][16];       // 256 B
            float  bbx[16][6];       // 384 B
        } s;
        unsigned long long karr[NPTS];  // 65536 B, phases 0-2 only (overlaps spts)
    } u;

    // ---- phase 0: batch bbox ----
    float mnx = FLT_MAX, mny = FLT_MAX, mnz = FLT_MAX;
    float mxx = -FLT_MAX, mxy = -FLT_MAX, mxz = -FLT_MAX;
    for (int j = 0; j < 8; j++) {
        int p = tid + (j << 10);
        float x = xb[p * 3], y = xb[p * 3 + 1], z = xb[p * 3 + 2];
        mnx = fminf(mnx, x); mny = fminf(mny, y); mnz = fminf(mnz, z);
        mxx = fmaxf(mxx, x); mxy = fmaxf(mxy, y); mxz = fmaxf(mxz, z);
    }
#pragma unroll
    for (int off = 32; off; off >>= 1) {
        mnx = fminf(mnx, __shfl_xor(mnx, off)); mny = fminf(mny, __shfl_xor(mny, off));
        mnz = fminf(mnz, __shfl_xor(mnz, off));
        mxx = fmaxf(mxx, __shfl_xor(mxx, off)); mxy = fmaxf(mxy, __shfl_xor(mxy, off));
        mxz = fmaxf(mxz, __shfl_xor(mxz, off));
    }
    if (lane == 0) {
        u.s.bbx[w][0] = mnx; u.s.bbx[w][1] = mny; u.s.bbx[w][2] = mnz;
        u.s.bbx[w][3] = mxx; u.s.bbx[w][4] = mxy; u.s.bbx[w][5] = mxz;
    }
    __syncthreads();
#pragma unroll
    for (int i = 0; i < 16; i++) {
        mnx = fminf(mnx, u.s.bbx[i][0]); mny = fminf(mny, u.s.bbx[i][1]);
        mnz = fminf(mnz, u.s.bbx[i][2]);
        mxx = fmaxf(mxx, u.s.bbx[i][3]); mxy = fmaxf(mxy, u.s.bbx[i][4]);
        mxz = fmaxf(mxz, u.s.bbx[i][5]);
    }
    float scx = 1023.0f / fmaxf(mxx - mnx, 1e-20f);
    float scy = 1023.0f / fmaxf(mxy - mny, 1e-20f);
    float scz = 1023.0f / fmaxf(mxz - mnz, 1e-20f);
    __syncthreads();

    // ---- phase 1: Morton keys + bitonic sort ----
    for (int j = 0; j < 8; j++) {
        int p = tid + (j << 10);
        float x = xb[p * 3], y = xb[p * 3 + 1], z = xb[p * 3 + 2];
        unsigned int ix = (unsigned int)min(1023, max(0, (int)((x - mnx) * scx)));
        unsigned int iy = (unsigned int)min(1023, max(0, (int)((y - mny) * scy)));
        unsigned int iz = (unsigned int)min(1023, max(0, (int)((z - mnz) * scz)));
        unsigned long long code = (unsigned long long)((mpart(ix) << 2) | (mpart(iy) << 1) | mpart(iz));
        u.karr[p] = (code << 13) | (unsigned long long)p;
    }
    __syncthreads();
    for (int k = 2; k <= NPTS; k <<= 1) {
        for (int jj = k >> 1; jj > 0; jj >>= 1) {
            for (int pos = tid; pos < NPTS; pos += 1024) {
                int l2 = pos ^ jj;
                if (l2 > pos) {
                    unsigned long long a = u.karr[pos], c = u.karr[l2];
                    bool up = ((pos & k) == 0);
                    if ((up && a > c) || (!up && a < c)) { u.karr[pos] = c; u.karr[l2] = a; }
                }
            }
            __syncthreads();
        }
    }

    // ---- phase 2: gather sorted points into swizzled LDS, per-thread box ----
    unsigned long long kk[8];
#pragma unroll
    for (int j = 0; j < 8; j++) kk[j] = u.karr[tid * 8 + j];
    __syncthreads();  // all karr reads done; spts writes may clobber it
    float blox = FLT_MAX, bloy = FLT_MAX, bloz = FLT_MAX;
    float bhix = -FLT_MAX, bhiy = -FLT_MAX, bhiz = -FLT_MAX;
    double dk[8];
#pragma unroll
    for (int j = 0; j < 8; j++) {
        int oi = (int)(kk[j] & 0x1FFFULL);
        float x = xb[oi * 3], y = xb[oi * 3 + 1], z = xb[oi * 3 + 2];
        int sp = tid * 8 + j;
        int slot = (sp >> 3) | ((sp & 7) << 10);
        u.s.spts[slot] = make_float4(x, y, z, __int_as_float(oi));
        blox = fminf(blox, x); bloy = fminf(bloy, y); bloz = fminf(bloz, z);
        bhix = fmaxf(bhix, x); bhiy = fmaxf(bhiy, y); bhiz = fmaxf(bhiz, z);
        dk[j] = packkey(1e10, sp);
    }
    if (tid == 0) fidx[b * NS] = 0;
    __syncthreads();

    // ---- phase 3: main loop ----
    float cxf = xb[0], cyf = xb[1], czf = xb[2];
    double cx = (double)cxf, cy = (double)cyf, cz = (double)czf;
    double tmax = packkey(1e10, tid * 8 + 7);
    double wm = 0.0;   // valid after first butterfly (t=1 always updates)
    for (int t = 1; t < NS; t++) {
        // conservative f32 skip test: provably no dk change for this cluster
        float exf = fmaxf(fmaxf(blox - cxf, cxf - bhix), 0.f);
        float eyf = fmaxf(fmaxf(bloy - cyf, cyf - bhiy), 0.f);
        float ezf = fmaxf(fmaxf(bloz - czf, czf - bhiz), 0.f);
        float dmsqf = fmaf(exf, exf, fmaf(eyf, eyf, ezf * ezf));
        double tupper = __longlong_as_double(__double_as_longlong(tmax) | 0x1FFFULL);
        bool doupd = !((double)dmsqf * 0.99999 > tupper);
        if (__any(doupd)) {
            if (doupd) {
                double t0 = 0.0, t1 = 0.0;
#pragma unroll
                for (int j = 0; j < 8; j += 2) {
                    float4 v0 = u.s.spts[tid | (j << 10)];
                    float4 v1 = u.s.spts[tid | ((j + 1) << 10)];
                    double dx0 = (double)v0.x - cx, dy0 = (double)v0.y - cy, dz0 = (double)v0.z - cz;
                    double d0 = fma(dx0, dx0, fma(dy0, dy0, dz0 * dz0));
                    double nk0 = fmin(dk[j], packkey(d0, tid * 8 + j));
                    dk[j] = nk0; t0 = fmax(t0, nk0);
                    double dx1 = (double)v1.x - cx, dy1 = (double)v1.y - cy, dz1 = (double)v1.z - cz;
                    double d1 = fma(dx1, dx1, fma(dy1, dy1, dz1 * dz1));
                    double nk1 = fmin(dk[j + 1], packkey(d1, tid * 8 + j + 1));
                    dk[j + 1] = nk1; t1 = fmax(t1, nk1);
                }
                tmax = fmax(t0, t1);
            }
            double m = tmax;
#pragma unroll
            for (int off = 32; off; off >>= 1)
                m = fmax(m, __shfl_xor(m, off));
            wm = m;
        }
        if (lane == 0) u.s.swd[t & 1][w] = wm;
        __syncthreads();
        double gv = u.s.swd[t & 1][lane & 15];
#pragma unroll
        for (int off = 8; off; off >>= 1)
            gv = fmax(gv, __shfl_xor(gv, off));
        int sp = (int)((unsigned int)__double_as_longlong(gv) & 0x1FFFu);
        float4 cw = u.s.spts[(sp >> 3) | ((sp & 7) << 10)];  // same addr: broadcast
        cxf = cw.x; cyf = cw.y; czf = cw.z;
        cx = (double)cxf; cy = (double)cyf; cz = (double)czf;
        if (tid == 0) fidx[b * NS + t] = __float_as_int(cw.w);
    }
}

// ---------------- brute-force kNN top-16, packed keys, 4-way ref split ----------------
#define KT2 1024
__global__ void __launch_bounds__(256) k_knn(const float* __restrict__ xin, const int* __restrict__ fidx,
                                             int* __restrict__ knn) {
    __shared__ double sxd[KT2], syd[KT2], szd[KT2];     // 24 KB
    __shared__ double mk[4][16][64];                     // 32 KB: [part][rank][query]
    int tid = threadIdx.x;
    int part = tid >> 6;
    int ql = tid & 63;
    int gq = blockIdx.x * 64 + ql;
    int b = gq >> 12;
    const float* xb = xin + (size_t)b * NPTS * 3;
    int qi = fidx[gq];
    double qx = (double)xb[qi * 3], qy = (double)xb[qi * 3 + 1], qz = (double)xb[qi * 3 + 2];
    double kd0 = DBL_MAX, kd1 = DBL_MAX, kd2 = DBL_MAX, kd3 = DBL_MAX,
           kd4 = DBL_MAX, kd5 = DBL_MAX, kd6 = DBL_MAX, kd7 = DBL_MAX,
           kd8 = DBL_MAX, kd9 = DBL_MAX, kd10 = DBL_MAX, kd11 = DBL_MAX,
           kd12 = DBL_MAX, kd13 = DBL_MAX, kd14 = DBL_MAX, kd15 = DBL_MAX;
    for (int tile = 0; tile < NPTS / KT2; tile++) {
        for (int m = tid; m < KT2; m += 256) {
            int gj = tile * KT2 + m;
            sxd[m] = (double)xb[gj * 3];
            syd[m] = (double)xb[gj * 3 + 1];
            szd[m] = (double)xb[gj * 3 + 2];
        }
        __syncthreads();
        int base = part * (KT2 / 4);
        for (int m = 0; m < KT2 / 4; m++) {
            int li = base + m;
            double dx = qx - sxd[li], dy = qy - syd[li], dz = qz - szd[li];
            double d = fma(dx, dx, fma(dy, dy, dz * dz));
            double key = __longlong_as_double(
                (__double_as_longlong(d) & 0xFFFFFFFFFFFFE000ULL)
                | (unsigned long long)(tile * KT2 + li));
            if (key < kd15) {
                kd15 = fmax(kd14, fmin(kd15, key)); kd14 = fmax(kd13, fmin(kd14, key));
                kd13 = fmax(kd12, fmin(kd13, key)); kd12 = fmax(kd11, fmin(kd12, key));
                kd11 = fmax(kd10, fmin(kd11, key)); kd10 = fmax(kd9,  fmin(kd10, key));
                kd9  = fmax(kd8,  fmin(kd9,  key)); kd8  = fmax(kd7,  fmin(kd8,  key));
                kd7  = fmax(kd6,  fmin(kd7,  key)); kd6  = fmax(kd5,  fmin(kd6,  key));
                kd5  = fmax(kd4,  fmin(kd5,  key)); kd4  = fmax(kd3,  fmin(kd4,  key));
                kd3  = fmax(kd2,  fmin(kd3,  key)); kd2  = fmax(kd1,  fmin(kd2,  key));
                kd1  = fmax(kd0,  fmin(kd1,  key)); kd0  = fmin(kd0,  key);
            }
        }
        __syncthreads();
    }
    mk[part][0][ql] = kd0;  mk[part][1][ql] = kd1;  mk[part][2][ql] = kd2;  mk[part][3][ql] = kd3;
    mk[part][4][ql] = kd4;  mk[part][5][ql] = kd5;  mk[part][6][ql] = kd6;  mk[part][7][ql] = kd7;
    mk[part][8][ql] = kd8;  mk[part][9][ql] = kd9;  mk[part][10][ql] = kd10; mk[part][11][ql] = kd11;
    mk[part][12][ql] = kd12; mk[part][13][ql] = kd13; mk[part][14][ql] = kd14; mk[part][15][ql] = kd15;
    __syncthreads();
    if (tid < 64) {
        int i0 = 0, i1 = 0, i2 = 0, i3 = 0;
        double h0 = mk[0][0][tid], h1 = mk[1][0][tid], h2 = mk[2][0][tid], h3 = mk[3][0][tid];
        int* outp = knn + (size_t)(blockIdx.x * 64 + tid) * 16;
#pragma unroll
        for (int k = 0; k < 16; k++) {
            double mm = fmin(fmin(h0, h1), fmin(h2, h3));
            outp[k] = (int)(__double_as_longlong(mm) & 0x1FFFULL);
            if (mm == h0)      { i0++; h0 = (i0 < 16) ? mk[0][i0][tid] : DBL_MAX; }
            else if (mm == h1) { i1++; h1 = (i1 < 16) ? mk[1][i1][tid] : DBL_MAX; }
            else if (mm == h2) { i2++; h2 = (i2 < 16) ? mk[2][i2][tid] : DBL_MAX; }
            else               { i3++; h3 = (i3 < 16) ? mk[3][i3][tid] : DBL_MAX; }
        }
    }
}

// ---------------- gather + maxpool(67) + conv3 (wave per point) ----------------
__global__ void __launch_bounds__(256) k_group(const float* __restrict__ xin, const float* __restrict__ feat,
                                               const int* __restrict__ fidx, const int* __restrict__ knn,
                                               const float* __restrict__ W3, const float* __restrict__ b3,
                                               float* __restrict__ y3, float* __restrict__ stats) {
    __shared__ float W3s[OUTC * CATC];
    __shared__ float x67[4][68];
    __shared__ float lsum[64], lsq[64];
    int tid = threadIdx.x, w = tid >> 6, lane = tid & 63;
    for (int i = tid; i < OUTC * CATC; i += 256) W3s[i] = W3[i];
    if (tid < 64) { lsum[tid] = 0.f; lsq[tid] = 0.f; }
    __syncthreads();
    float psum = 0.f, psq = 0.f;
    int p0 = blockIdx.x * 64 + w * 16;
    for (int it = 0; it < 16; it++) {
        int p = p0 + it;
        int b = p >> 12;
        int myidx = knn[p * 16 + (lane & 15)];
        int nbk[16];
#pragma unroll
        for (int k = 0; k < 16; k++) nbk[k] = __shfl(myidx, k);
        float m = -FLT_MAX;
#pragma unroll
        for (int k = 0; k < 16; k++) m = fmaxf(m, feat[(size_t)(b * NPTS + nbk[k]) * OUTC + lane]);
        x67[w][3 + lane] = m;
        if (lane < 3) {
            int ci = fidx[p];
            float cc = xin[(size_t)(b * NPTS + ci) * 3 + lane];
            float mg = -FLT_MAX;
#pragma unroll
            for (int k = 0; k < 16; k++) mg = fmaxf(mg, xin[(size_t)(b * NPTS + nbk[k]) * 3 + lane] - cc);
            x67[w][lane] = mg;
        }
        __syncthreads();
        float acc = b3[lane];
#pragma unroll
        for (int c = 0; c < CATC; c++) acc = fmaf(W3s[lane * CATC + c], x67[w][c], acc);
        y3[(size_t)p * OUTC + lane] = acc;
        psum += acc; psq = fmaf(acc, acc, psq);
        __syncthreads();
    }
    atomicAdd(&lsum[lane], psum);
    atomicAdd(&lsq[lane], psq);
    __syncthreads();
    if (tid < 64) { atomicAdd(&stats[64 + tid], lsum[tid]); atomicAdd(&stats[128 + tid], lsq[tid]); }
}

// ---------------- BN2 finalize ----------------
__global__ void k_stats2(float* __restrict__ stats) {
    int c = threadIdx.x;  // 64
    float m = stats[64 + c] / (float)TOTAL_S;
    float var = stats[128 + c] / (float)TOTAL_S - m * m;
    stats[192 + c] = m;
    stats[256 + c] = rsqrtf(var + BN_EPS);
}

// ---------------- final conv with fused BN2+ReLU: out = relu(bn(y3)) @ W4^T + b4 ----------------
__global__ void __launch_bounds__(256) k_last(const float* __restrict__ y3, const float* __restrict__ stats,
                                              const float* __restrict__ g2, const float* __restrict__ be2,
                                              const float* __restrict__ W4, const float* __restrict__ b4,
                                              float* __restrict__ out) {
    __shared__ float W4t[OUTC * OUTC];
    __shared__ float xs[4][64];
    int tid = threadIdx.x;
    for (int i = tid; i < OUTC * OUTC; i += 256) W4t[(i & 63) * 64 + (i >> 6)] = W4[i];
    int lp = tid >> 6, o = tid & 63;
    int p = blockIdx.x * 4 + lp;
    float v = y3[(size_t)p * OUTC + o];
    v = fmaf((v - stats[192 + o]) * stats[256 + o], g2[o], be2[o]);
    xs[lp][o] = fmaxf(v, 0.f);
    __syncthreads();
    const float* xp = xs[lp];
    float acc = b4[o];
#pragma unroll
    for (int c = 0; c < OUTC; c++) acc = fmaf(W4t[c * 64 + o], xp[c], acc);
    out[(size_t)p * OUTC + o] = acc;
}

extern "C" void kernel_launch(void* const* d_in, const int* in_sizes, int n_in,
                              void* d_out, int out_size, void* d_ws, size_t ws_size,
                              hipStream_t stream) {
    const float* xin = (const float*)d_in[0];
    const float* W1  = (const float*)d_in[1];
    const float* b1  = (const float*)d_in[2];
    const float* g1  = (const float*)d_in[3];
    const float* be1 = (const float*)d_in[4];
    const float* W2  = (const float*)d_in[5];
    const float* b2  = (const float*)d_in[6];
    const float* W3  = (const float*)d_in[7];
    const float* b3  = (const float*)d_in[8];
    const float* g2  = (const float*)d_in[9];
    const float* be2 = (const float*)d_in[10];
    const float* W4  = (const float*)d_in[11];
    const float* b4  = (const float*)d_in[12];
    float* out = (float*)d_out;

    float* ws = (float*)d_ws;
    float* t1   = ws;                                       // 32*32768   = 1,048,576 f
    float* feat = t1 + (size_t)MIDC * TOTAL_PTS;            // 32768*64   = 2,097,152 f
    int*   fidx = (int*)(feat + (size_t)TOTAL_PTS * OUTC);  // 16384 i
    int*   knn  = fidx + TOTAL_S;                           // 16384*16   = 262,144 i
    float* y3   = (float*)(knn + (size_t)TOTAL_S * 16);     // 16384*64   = 1,048,576 f
    float* stats = y3 + (size_t)TOTAL_S * OUTC;             // 320 f

    k_first<<<TOTAL_PTS / 256, 256, 0, stream>>>(xin, W1, b1, t1);
    k_stats1<<<MIDC, 256, 0, stream>>>(t1, stats);
    k_feat<<<TOTAL_PTS / 256, 256, 0, stream>>>(t1, stats, g1, be1, W2, b2, feat);
    k_fps<<<NB, 1024, 0, stream>>>(xin, fidx);
    k_knn<<<TOTAL_S / 64, 256, 0, stream>>>(xin, fidx, knn);
    k_group<<<TOTAL_S / 64, 256, 0, stream>>>(xin, feat, fidx, knn, W3, b3, y3, stats);
    k_stats2<<<1, 64, 0, stream>>>(stats);
    k_last<<<TOTAL_S / 4, 256, 0, stream>>>(y3, stats, g2, be2, W4, b4, out);
}

// Round 11
// 3782.121 us; speedup vs baseline: 1.6826x; 1.3673x over previous
//
#include <hip/hip_runtime.h>
#include <float.h>
#include <math.h>

#define NB 4
#define NPTS 8192
#define NS 4096
#define MIDC 32
#define OUTC 64
#define CATC 67
#define BN_EPS 1e-5f
#define TOTAL_PTS (NB*NPTS)   // 32768
#define TOTAL_S (NB*NS)       // 16384

// Packed selection key: for non-negative doubles the IEEE754 bit pattern is
// order-isomorphic to the value. Truncate the low 13 mantissa bits (2^-39 rel
// noise vs ~1e-4 boundary gaps) and store a 13-bit id there: (dist,id) compare
// becomes one f64 compare, and min-update is a single fmin.

__device__ __forceinline__ double packkey(double d, int sp) {
    return __longlong_as_double((__double_as_longlong(d) & 0xFFFFFFFFFFFFE000ULL)
                                | (unsigned long long)sp);
}

// f64 max with a DPP-moved partner (VALU-speed cross-lane; ~3x lower latency
// than ds_permute-based __shfl_xor). Keys are >= 0 so old=0 for masked rows
// is identity under fmax.
template<int CTRL, int RM>
__device__ __forceinline__ double dpp_fmax64(double v) {
    int lo = __builtin_amdgcn_update_dpp(0, __double2loint(v), CTRL, RM, 0xF, false);
    int hi = __builtin_amdgcn_update_dpp(0, __double2hiint(v), CTRL, RM, 0xF, false);
    return fmax(v, __hiloint2double(hi, lo));
}

// ---------------- first conv: t1[c][p] = x_in[p] . W1[c] + b1[c] ----------------
__global__ void k_first(const float* __restrict__ xin, const float* __restrict__ W1,
                        const float* __restrict__ b1, float* __restrict__ t1) {
    int p = blockIdx.x * blockDim.x + threadIdx.x;  // 0..32767
    float x = xin[p * 3], y = xin[p * 3 + 1], z = xin[p * 3 + 2];
#pragma unroll
    for (int c = 0; c < MIDC; c++) {
        float v = fmaf(W1[c * 3 + 2], z, fmaf(W1[c * 3 + 1], y, fmaf(W1[c * 3], x, b1[c])));
        t1[c * TOTAL_PTS + p] = v;
    }
}

// ---------------- BN1 stats: one block per channel (+ zero stats[64..320)) ----------------
__global__ void k_stats1(const float* __restrict__ t1, float* __restrict__ stats) {
    int c = blockIdx.x, tid = threadIdx.x;
    if (tid < 8) stats[64 + c * 8 + tid] = 0.f;   // ws is poisoned 0xAA each call
    float s = 0.f, ss = 0.f;
    for (int i = tid; i < TOTAL_PTS; i += 256) {
        float v = t1[c * TOTAL_PTS + i];
        s += v; ss = fmaf(v, v, ss);
    }
#pragma unroll
    for (int off = 32; off; off >>= 1) { s += __shfl_down(s, off); ss += __shfl_down(ss, off); }
    __shared__ float ls[4], lss[4];
    int w = tid >> 6, lane = tid & 63;
    if (lane == 0) { ls[w] = s; lss[w] = ss; }
    __syncthreads();
    if (tid == 0) {
        s = ls[0] + ls[1] + ls[2] + ls[3];
        ss = lss[0] + lss[1] + lss[2] + lss[3];
        float m = s / (float)TOTAL_PTS;
        float var = ss / (float)TOTAL_PTS - m * m;
        stats[c] = m;
        stats[32 + c] = rsqrtf(var + BN_EPS);
    }
}

// ---------------- BN1+ReLU then second conv: feat[p][o] ----------------
__global__ void __launch_bounds__(256) k_feat(const float* __restrict__ t1, const float* __restrict__ stats,
                                              const float* __restrict__ g1, const float* __restrict__ be1,
                                              const float* __restrict__ W2, const float* __restrict__ b2,
                                              float* __restrict__ feat) {
    __shared__ float W2s[OUTC * MIDC];
    for (int i = threadIdx.x; i < OUTC * MIDC; i += 256) W2s[i] = W2[i];
    __syncthreads();
    int p = blockIdx.x * blockDim.x + threadIdx.x;
    float h[MIDC];
#pragma unroll
    for (int c = 0; c < MIDC; c++) {
        float v = t1[c * TOTAL_PTS + p];
        v = fmaf((v - stats[c]) * stats[32 + c], g1[c], be1[c]);
        h[c] = fmaxf(v, 0.f);
    }
#pragma unroll 4
    for (int o = 0; o < OUTC; o++) {
        float a = b2[o];
#pragma unroll
        for (int c = 0; c < MIDC; c++) a = fmaf(W2s[o * MIDC + c], h[c], a);
        feat[p * OUTC + o] = a;
    }
}

// ---------------- farthest point sampling: Morton-clustered lazy-exact ----------------
// 1024 threads x 8 pts. r10 post-mortem: floor = cross-lane latency
// (shfl butterfly = ds_permute ~50cyc/level) + update's LDS feed.
// This round: (1) points stay in VGPRs (produced in phase 2; 24 regs;
// __launch_bounds__(1024,4) grants 128-reg budget); LDS spts only for the
// centroid broadcast. (2) All reduces via DPP row_ror/row_bcast + readlane
// (VALU-speed). Max is exact -> selection sequence bit-identical.
__device__ __forceinline__ unsigned int mpart(unsigned int x) {
    x &= 1023u;
    x = (x | (x << 16)) & 0x030000FFu;
    x = (x | (x << 8))  & 0x0300F00Fu;
    x = (x | (x << 4))  & 0x030C30C3u;
    x = (x | (x << 2))  & 0x09249249u;
    return x;
}

__global__ void __launch_bounds__(1024, 4) k_fps(const float* __restrict__ xin, int* __restrict__ fidx) {
    const int b = blockIdx.x;
    const int tid = threadIdx.x;
    const int lane = tid & 63, w = tid >> 6;  // 16 waves
    const float* xb = xin + (size_t)b * NPTS * 3;
    __shared__ union UU {
        struct SS {
            float4 spts[NPTS];       // 131072 B, swizzled, .w = orig idx bits
            double swd[2][16];       // 256 B
            float  bbx[16][6];       // 384 B
        } s;
        unsigned long long karr[NPTS];  // 65536 B, phases 0-2 only (overlaps spts)
    } u;

    // ---- phase 0: batch bbox ----
    float mnx = FLT_MAX, mny = FLT_MAX, mnz = FLT_MAX;
    float mxx = -FLT_MAX, mxy = -FLT_MAX, mxz = -FLT_MAX;
    for (int j = 0; j < 8; j++) {
        int p = tid + (j << 10);
        float x = xb[p * 3], y = xb[p * 3 + 1], z = xb[p * 3 + 2];
        mnx = fminf(mnx, x); mny = fminf(mny, y); mnz = fminf(mnz, z);
        mxx = fmaxf(mxx, x); mxy = fmaxf(mxy, y); mxz = fmaxf(mxz, z);
    }
#pragma unroll
    for (int off = 32; off; off >>= 1) {
        mnx = fminf(mnx, __shfl_xor(mnx, off)); mny = fminf(mny, __shfl_xor(mny, off));
        mnz = fminf(mnz, __shfl_xor(mnz, off));
        mxx = fmaxf(mxx, __shfl_xor(mxx, off)); mxy = fmaxf(mxy, __shfl_xor(mxy, off));
        mxz = fmaxf(mxz, __shfl_xor(mxz, off));
    }
    if (lane == 0) {
        u.s.bbx[w][0] = mnx; u.s.bbx[w][1] = mny; u.s.bbx[w][2] = mnz;
        u.s.bbx[w][3] = mxx; u.s.bbx[w][4] = mxy; u.s.bbx[w][5] = mxz;
    }
    __syncthreads();
#pragma unroll
    for (int i = 0; i < 16; i++) {
        mnx = fminf(mnx, u.s.bbx[i][0]); mny = fminf(mny, u.s.bbx[i][1]);
        mnz = fminf(mnz, u.s.bbx[i][2]);
        mxx = fmaxf(mxx, u.s.bbx[i][3]); mxy = fmaxf(mxy, u.s.bbx[i][4]);
        mxz = fmaxf(mxz, u.s.bbx[i][5]);
    }
    float scx = 1023.0f / fmaxf(mxx - mnx, 1e-20f);
    float scy = 1023.0f / fmaxf(mxy - mny, 1e-20f);
    float scz = 1023.0f / fmaxf(mxz - mnz, 1e-20f);
    __syncthreads();

    // ---- phase 1: Morton keys + bitonic sort ----
    for (int j = 0; j < 8; j++) {
        int p = tid + (j << 10);
        float x = xb[p * 3], y = xb[p * 3 + 1], z = xb[p * 3 + 2];
        unsigned int ix = (unsigned int)min(1023, max(0, (int)((x - mnx) * scx)));
        unsigned int iy = (unsigned int)min(1023, max(0, (int)((y - mny) * scy)));
        unsigned int iz = (unsigned int)min(1023, max(0, (int)((z - mnz) * scz)));
        unsigned long long code = (unsigned long long)((mpart(ix) << 2) | (mpart(iy) << 1) | mpart(iz));
        u.karr[p] = (code << 13) | (unsigned long long)p;
    }
    __syncthreads();
    for (int k = 2; k <= NPTS; k <<= 1) {
        for (int jj = k >> 1; jj > 0; jj >>= 1) {
            for (int pos = tid; pos < NPTS; pos += 1024) {
                int l2 = pos ^ jj;
                if (l2 > pos) {
                    unsigned long long a = u.karr[pos], c = u.karr[l2];
                    bool up = ((pos & k) == 0);
                    if ((up && a > c) || (!up && a < c)) { u.karr[pos] = c; u.karr[l2] = a; }
                }
            }
            __syncthreads();
        }
    }

    // ---- phase 2: gather sorted points into regs + swizzled LDS, per-thread box ----
    unsigned long long kk[8];
#pragma unroll
    for (int j = 0; j < 8; j++) kk[j] = u.karr[tid * 8 + j];
    __syncthreads();  // all karr reads done; spts writes may clobber it
    float blox = FLT_MAX, bloy = FLT_MAX, bloz = FLT_MAX;
    float bhix = -FLT_MAX, bhiy = -FLT_MAX, bhiz = -FLT_MAX;
    float prx[8], pry[8], prz[8];
    double dk[8];
#pragma unroll
    for (int j = 0; j < 8; j++) {
        int oi = (int)(kk[j] & 0x1FFFULL);
        float x = xb[oi * 3], y = xb[oi * 3 + 1], z = xb[oi * 3 + 2];
        int sp = tid * 8 + j;
        int slot = (sp >> 3) | ((sp & 7) << 10);
        u.s.spts[slot] = make_float4(x, y, z, __int_as_float(oi));
        prx[j] = x; pry[j] = y; prz[j] = z;
        blox = fminf(blox, x); bloy = fminf(bloy, y); bloz = fminf(bloz, z);
        bhix = fmaxf(bhix, x); bhiy = fmaxf(bhiy, y); bhiz = fmaxf(bhiz, z);
        dk[j] = packkey(1e10, sp);
    }
    if (tid == 0) fidx[b * NS] = 0;
    __syncthreads();

    // ---- phase 3: main loop ----
    float cxf = xb[0], cyf = xb[1], czf = xb[2];
    double cx = (double)cxf, cy = (double)cyf, cz = (double)czf;
    double tmax = packkey(1e10, tid * 8 + 7);
    double wm = 0.0;   // valid after first reduce (t=1 always updates)
    for (int t = 1; t < NS; t++) {
        // conservative f32 skip test: provably no dk change for this cluster
        float exf = fmaxf(fmaxf(blox - cxf, cxf - bhix), 0.f);
        float eyf = fmaxf(fmaxf(bloy - cyf, cyf - bhiy), 0.f);
        float ezf = fmaxf(fmaxf(bloz - czf, czf - bhiz), 0.f);
        float dmsqf = fmaf(exf, exf, fmaf(eyf, eyf, ezf * ezf));
        double tupper = __longlong_as_double(__double_as_longlong(tmax) | 0x1FFFULL);
        bool doupd = !((double)dmsqf * 0.99999 > tupper);
        if (__any(doupd)) {
            if (doupd) {
                double t0 = 0.0, t1 = 0.0;
#pragma unroll
                for (int j = 0; j < 8; j += 2) {
                    double dx0 = (double)prx[j] - cx, dy0 = (double)pry[j] - cy, dz0 = (double)prz[j] - cz;
                    double d0 = fma(dx0, dx0, fma(dy0, dy0, dz0 * dz0));
                    double nk0 = fmin(dk[j], packkey(d0, tid * 8 + j));
                    dk[j] = nk0; t0 = fmax(t0, nk0);
                    double dx1 = (double)prx[j + 1] - cx, dy1 = (double)pry[j + 1] - cy, dz1 = (double)prz[j + 1] - cz;
                    double d1 = fma(dx1, dx1, fma(dy1, dy1, dz1 * dz1));
                    double nk1 = fmin(dk[j + 1], packkey(d1, tid * 8 + j + 1));
                    dk[j + 1] = nk1; t1 = fmax(t1, nk1);
                }
                tmax = fmax(t0, t1);
            }
            // wave max via DPP: 4x row_ror -> row max; bcast15/31 -> lane 63 total
            double v = tmax;
            v = dpp_fmax64<0x121, 0xF>(v);
            v = dpp_fmax64<0x122, 0xF>(v);
            v = dpp_fmax64<0x124, 0xF>(v);
            v = dpp_fmax64<0x128, 0xF>(v);
            v = dpp_fmax64<0x142, 0xa>(v);
            v = dpp_fmax64<0x143, 0x8>(v);
            int wlo = __builtin_amdgcn_readlane(__double2loint(v), 63);
            int whi = __builtin_amdgcn_readlane(__double2hiint(v), 63);
            wm = __hiloint2double(whi, wlo);
        }
        if (lane == 0) u.s.swd[t & 1][w] = wm;
        __syncthreads();
        // cross-wave max: 16 values replicated per row -> 4 DPP ror levels
        double gv = u.s.swd[t & 1][lane & 15];
        gv = dpp_fmax64<0x121, 0xF>(gv);
        gv = dpp_fmax64<0x122, 0xF>(gv);
        gv = dpp_fmax64<0x124, 0xF>(gv);
        gv = dpp_fmax64<0x128, 0xF>(gv);
        int sp = (int)((unsigned int)__double_as_longlong(gv) & 0x1FFFu);
        float4 cw = u.s.spts[(sp >> 3) | ((sp & 7) << 10)];  // same addr: broadcast
        cxf = cw.x; cyf = cw.y; czf = cw.z;
        cx = (double)cxf; cy = (double)cyf; cz = (double)czf;
        if (tid == 0) fidx[b * NS + t] = __float_as_int(cw.w);
    }
}

// ---------------- brute-force kNN top-16, packed keys, 4-way ref split ----------------
#define KT2 1024
__global__ void __launch_bounds__(256) k_knn(const float* __restrict__ xin, const int* __restrict__ fidx,
                                             int* __restrict__ knn) {
    __shared__ double sxd[KT2], syd[KT2], szd[KT2];     // 24 KB
    __shared__ double mk[4][16][64];                     // 32 KB: [part][rank][query]
    int tid = threadIdx.x;
    int part = tid >> 6;
    int ql = tid & 63;
    int gq = blockIdx.x * 64 + ql;
    int b = gq >> 12;
    const float* xb = xin + (size_t)b * NPTS * 3;
    int qi = fidx[gq];
    double qx = (double)xb[qi * 3], qy = (double)xb[qi * 3 + 1], qz = (double)xb[qi * 3 + 2];
    double kd0 = DBL_MAX, kd1 = DBL_MAX, kd2 = DBL_MAX, kd3 = DBL_MAX,
           kd4 = DBL_MAX, kd5 = DBL_MAX, kd6 = DBL_MAX, kd7 = DBL_MAX,
           kd8 = DBL_MAX, kd9 = DBL_MAX, kd10 = DBL_MAX, kd11 = DBL_MAX,
           kd12 = DBL_MAX, kd13 = DBL_MAX, kd14 = DBL_MAX, kd15 = DBL_MAX;
    for (int tile = 0; tile < NPTS / KT2; tile++) {
        for (int m = tid; m < KT2; m += 256) {
            int gj = tile * KT2 + m;
            sxd[m] = (double)xb[gj * 3];
            syd[m] = (double)xb[gj * 3 + 1];
            szd[m] = (double)xb[gj * 3 + 2];
        }
        __syncthreads();
        int base = part * (KT2 / 4);
        for (int m = 0; m < KT2 / 4; m++) {
            int li = base + m;
            double dx = qx - sxd[li], dy = qy - syd[li], dz = qz - szd[li];
            double d = fma(dx, dx, fma(dy, dy, dz * dz));
            double key = __longlong_as_double(
                (__double_as_longlong(d) & 0xFFFFFFFFFFFFE000ULL)
                | (unsigned long long)(tile * KT2 + li));
            if (key < kd15) {
                kd15 = fmax(kd14, fmin(kd15, key)); kd14 = fmax(kd13, fmin(kd14, key));
                kd13 = fmax(kd12, fmin(kd13, key)); kd12 = fmax(kd11, fmin(kd12, key));
                kd11 = fmax(kd10, fmin(kd11, key)); kd10 = fmax(kd9,  fmin(kd10, key));
                kd9  = fmax(kd8,  fmin(kd9,  key)); kd8  = fmax(kd7,  fmin(kd8,  key));
                kd7  = fmax(kd6,  fmin(kd7,  key)); kd6  = fmax(kd5,  fmin(kd6,  key));
                kd5  = fmax(kd4,  fmin(kd5,  key)); kd4  = fmax(kd3,  fmin(kd4,  key));
                kd3  = fmax(kd2,  fmin(kd3,  key)); kd2  = fmax(kd1,  fmin(kd2,  key));
                kd1  = fmax(kd0,  fmin(kd1,  key)); kd0  = fmin(kd0,  key);
            }
        }
        __syncthreads();
    }
    mk[part][0][ql] = kd0;  mk[part][1][ql] = kd1;  mk[part][2][ql] = kd2;  mk[part][3][ql] = kd3;
    mk[part][4][ql] = kd4;  mk[part][5][ql] = kd5;  mk[part][6][ql] = kd6;  mk[part][7][ql] = kd7;
    mk[part][8][ql] = kd8;  mk[part][9][ql] = kd9;  mk[part][10][ql] = kd10; mk[part][11][ql] = kd11;
    mk[part][12][ql] = kd12; mk[part][13][ql] = kd13; mk[part][14][ql] = kd14; mk[part][15][ql] = kd15;
    __syncthreads();
    if (tid < 64) {
        int i0 = 0, i1 = 0, i2 = 0, i3 = 0;
        double h0 = mk[0][0][tid], h1 = mk[1][0][tid], h2 = mk[2][0][tid], h3 = mk[3][0][tid];
        int* outp = knn + (size_t)(blockIdx.x * 64 + tid) * 16;
#pragma unroll
        for (int k = 0; k < 16; k++) {
            double mm = fmin(fmin(h0, h1), fmin(h2, h3));
            outp[k] = (int)(__double_as_longlong(mm) & 0x1FFFULL);
            if (mm == h0)      { i0++; h0 = (i0 < 16) ? mk[0][i0][tid] : DBL_MAX; }
            else if (mm == h1) { i1++; h1 = (i1 < 16) ? mk[1][i1][tid] : DBL_MAX; }
            else if (mm == h2) { i2++; h2 = (i2 < 16) ? mk[2][i2][tid] : DBL_MAX; }
            else               { i3++; h3 = (i3 < 16) ? mk[3][i3][tid] : DBL_MAX; }
        }
    }
}

// ---------------- gather + maxpool(67) + conv3 (wave per point) ----------------
__global__ void __launch_bounds__(256) k_group(const float* __restrict__ xin, const float* __restrict__ feat,
                                               const int* __restrict__ fidx, const int* __restrict__ knn,
                                               const float* __restrict__ W3, const float* __restrict__ b3,
                                               float* __restrict__ y3, float* __restrict__ stats) {
    __shared__ float W3s[OUTC * CATC];
    __shared__ float x67[4][68];
    __shared__ float lsum[64], lsq[64];
    int tid = threadIdx.x, w = tid >> 6, lane = tid & 63;
    for (int i = tid; i < OUTC * CATC; i += 256) W3s[i] = W3[i];
    if (tid < 64) { lsum[tid] = 0.f; lsq[tid] = 0.f; }
    __syncthreads();
    float psum = 0.f, psq = 0.f;
    int p0 = blockIdx.x * 64 + w * 16;
    for (int it = 0; it < 16; it++) {
        int p = p0 + it;
        int b = p >> 12;
        int myidx = knn[p * 16 + (lane & 15)];
        int nbk[16];
#pragma unroll
        for (int k = 0; k < 16; k++) nbk[k] = __shfl(myidx, k);
        float m = -FLT_MAX;
#pragma unroll
        for (int k = 0; k < 16; k++) m = fmaxf(m, feat[(size_t)(b * NPTS + nbk[k]) * OUTC + lane]);
        x67[w][3 + lane] = m;
        if (lane < 3) {
            int ci = fidx[p];
            float cc = xin[(size_t)(b * NPTS + ci) * 3 + lane];
            float mg = -FLT_MAX;
#pragma unroll
            for (int k = 0; k < 16; k++) mg = fmaxf(mg, xin[(size_t)(b * NPTS + nbk[k]) * 3 + lane] - cc);
            x67[w][lane] = mg;
        }
        __syncthreads();
        float acc = b3[lane];
#pragma unroll
        for (int c = 0; c < CATC; c++) acc = fmaf(W3s[lane * CATC + c], x67[w][c], acc);
        y3[(size_t)p * OUTC + lane] = acc;
        psum += acc; psq = fmaf(acc, acc, psq);
        __syncthreads();
    }
    atomicAdd(&lsum[lane], psum);
    atomicAdd(&lsq[lane], psq);
    __syncthreads();
    if (tid < 64) { atomicAdd(&stats[64 + tid], lsum[tid]); atomicAdd(&stats[128 + tid], lsq[tid]); }
}

// ---------------- BN2 finalize ----------------
__global__ void k_stats2(float* __restrict__ stats) {
    int c = threadIdx.x;  // 64
    float m = stats[64 + c] / (float)TOTAL_S;
    float var = stats[128 + c] / (float)TOTAL_S - m * m;
    stats[192 + c] = m;
    stats[256 + c] = rsqrtf(var + BN_EPS);
}

// ---------------- final conv with fused BN2+ReLU: out = relu(bn(y3)) @ W4^T + b4 ----------------
__global__ void __launch_bounds__(256) k_last(const float* __restrict__ y3, const float* __restrict__ stats,
                                              const float* __restrict__ g2, const float* __restrict__ be2,
                                              const float* __restrict__ W4, const float* __restrict__ b4,
                                              float* __restrict__ out) {
    __shared__ float W4t[OUTC * OUTC];
    __shared__ float xs[4][64];
    int tid = threadIdx.x;
    for (int i = tid; i < OUTC * OUTC; i += 256) W4t[(i & 63) * 64 + (i >> 6)] = W4[i];
    int lp = tid >> 6, o = tid & 63;
    int p = blockIdx.x * 4 + lp;
    float v = y3[(size_t)p * OUTC + o];
    v = fmaf((v - stats[192 + o]) * stats[256 + o], g2[o], be2[o]);
    xs[lp][o] = fmaxf(v, 0.f);
    __syncthreads();
    const float* xp = xs[lp];
    float acc = b4[o];
#pragma unroll
    for (int c = 0; c < OUTC; c++) acc = fmaf(W4t[c * 64 + o], xp[c], acc);
    out[(size_t)p * OUTC + o] = acc;
}

extern "C" void kernel_launch(void* const* d_in, const int* in_sizes, int n_in,
                              void* d_out, int out_size, void* d_ws, size_t ws_size,
                              hipStream_t stream) {
    const float* xin = (const float*)d_in[0];
    const float* W1  = (const float*)d_in[1];
    const float* b1  = (const float*)d_in[2];
    const float* g1  = (const float*)d_in[3];
    const float* be1 = (const float*)d_in[4];
    const float* W2  = (const float*)d_in[5];
    const float* b2  = (const float*)d_in[6];
    const float* W3  = (const float*)d_in[7];
    const float* b3  = (const float*)d_in[8];
    const float* g2  = (const float*)d_in[9];
    const float* be2 = (const float*)d_in[10];
    const float* W4  = (const float*)d_in[11];
    const float* b4  = (const float*)d_in[12];
    float* out = (float*)d_out;

    float* ws = (float*)d_ws;
    float* t1   = ws;                                       // 32*32768   = 1,048,576 f
    float* feat = t1 + (size_t)MIDC * TOTAL_PTS;            // 32768*64   = 2,097,152 f
    int*   fidx = (int*)(feat + (size_t)TOTAL_PTS * OUTC);  // 16384 i
    int*   knn  = fidx + TOTAL_S;                           // 16384*16   = 262,144 i
    float* y3   = (float*)(knn + (size_t)TOTAL_S * 16);     // 16384*64   = 1,048,576 f
    float* stats = y3 + (size_t)TOTAL_S * OUTC;             // 320 f

    k_first<<<TOTAL_PTS / 256, 256, 0, stream>>>(xin, W1, b1, t1);
    k_stats1<<<MIDC, 256, 0, stream>>>(t1, stats);
    k_feat<<<TOTAL_PTS / 256, 256, 0, stream>>>(t1, stats, g1, be1, W2, b2, feat);
    k_fps<<<NB, 1024, 0, stream>>>(xin, fidx);
    k_knn<<<TOTAL_S / 64, 256, 0, stream>>>(xin, fidx, knn);
    k_group<<<TOTAL_S / 64, 256, 0, stream>>>(xin, feat, fidx, knn, W3, b3, y3, stats);
    k_stats2<<<1, 64, 0, stream>>>(stats);
    k_last<<<TOTAL_S / 4, 256, 0, stream>>>(y3, stats, g2, be2, W4, b4, out);
}